// Round 14
// baseline (364.715 us; speedup 1.0000x reference)
//
#include <hip/hip_runtime.h>
#include <hip/hip_bf16.h>

#define BATCH 32
#define CH 3
#define HH 256
#define WW 256
#define KS 29
#define PAD 14
#define NT_F 1000.0f

typedef __attribute__((ext_vector_type(8))) short short8;
typedef __attribute__((ext_vector_type(4))) float f32x4;
typedef __attribute__((ext_vector_type(16))) float f32x16;

union U4 { short8 s8; uint4 u4; };

__device__ inline unsigned short bf16rne(float f) {
  unsigned u = __float_as_uint(f);
  unsigned r = (u + 0x7FFFu + ((u >> 16) & 1u)) >> 16;
  return (unsigned short)r;
}
__device__ inline unsigned pk_bf16(float a, float b) {
  union { __hip_bfloat162 h2; unsigned u; } cv;
  cv.h2 = __float22bfloat162_rn(make_float2(a, b));
  return cv.u;
}

// ws float layout:
//   (unused)  [1024]          @ 0
//   tcond [32][32]            @ 1024
//   w1n   ushort[3][32][16]   @ 2048  ([mf][och][slot]; slot s: tap=mf*4+(s>>2), ci=s&3)
//   w2c   ushort[9][16][32]   @ 2816  ([tap][oc(16)][och] plain order)
//   z     ushort[32][3][256][256] @ 5120  (bf16 blurred)
//   partial float[8192]       @ 3151872
//   counter int               @ 3160064  (zeroed by prep block; last-block reduce)
//
// conv1 (32x32x16 MFMA): A=weights[m=och][k=slot], B=z[k=slot][n=pixel],
//   D[n=pixel=lane&31][m=och=(reg&3)+8*(reg>>2)+4*(lane>>5)]
// conv2 (16x16x32 MFMA): hs & w2c in plain och order.

#define PARTIAL_OFF 3151872
#define COUNTER_OFF 3160064

// ---------------- blur (+ embedded weight-prep in block 768) ----------------
__global__ __launch_bounds__(256, 3) void blur_kernel(
    const float* __restrict__ x, const int* __restrict__ t,
    const float* __restrict__ sched, const float* __restrict__ W1,
    const float* __restrict__ b1, const float* __restrict__ tw,
    const float* __restrict__ W2, float* __restrict__ ws,
    unsigned short* __restrict__ z) {
  int blk = blockIdx.x;
  int tid = threadIdx.x;

  if (blk >= BATCH * CH * 8) {
    // ---- weight-prep block (runs once; convloss launches after this kernel)
    float* tcond = ws + 1024;
    unsigned short* w1n = (unsigned short*)(ws + 2048);
    unsigned short* w2c = (unsigned short*)(ws + 2816);
    if (tid == 0) *(int*)(ws + COUNTER_OFF) = 0;     // zero last-block counter
    for (int i = tid; i < 1536; i += 256) {          // w1n [mf][och][slot]
      int mf = i >> 9, r = i & 511;
      int och = r >> 4, s = r & 15;
      int tp = mf * 4 + (s >> 2), ci = s & 3;
      w1n[i] = (ci < 3 && tp < 9) ? bf16rne(W1[och * 27 + ci * 9 + tp])
                                  : (unsigned short)0;
    }
    for (int i = tid; i < 4608; i += 256) {          // w2c [tap][oc][och] plain
      int tap = i >> 9, r = i & 511;
      int n = r >> 5, och = r & 31;
      int dy = tap / 3, dx = tap - dy * 3;
      w2c[i] = (n < 3) ? bf16rne(W2[((n * 32 + och) * 3 + dy) * 3 + dx])
                       : (unsigned short)0;
    }
    for (int i = tid; i < 1024; i += 256) {          // tcond
      int b = i >> 5, o = i & 31;
      tcond[i] = b1[o] + ((float)t[b] * (1.0f / NT_F)) * tw[o];
    }
    return;
  }

  __shared__ float vsp[32][288];   // padded cols: idx = col + 16
  __shared__ float gkl[32];
  int rg = blk & 7;
  int bc = blk >> 3;
  int b = bc / CH;
  int y0 = rg * 32;
  const float* xp = x + (size_t)bc * (HH * WW);

  // issue the 60 column loads first (independent of gk)
  float xv[60];
#pragma unroll
  for (int i = 0; i < 60; i++) {
    int gy = y0 - PAD + i;
    gy = (gy < 0) ? -gy : gy;
    gy = (gy >= HH) ? (2 * HH - 2 - gy) : gy;
    xv[i] = xp[gy * WW + tid];
  }

  // wave 0 computes this batch's gaussian kernel into LDS
  if (tid < 64) {
    float wexp = 0.0f;
    if (tid < KS) {
      float sigma = sched[t[b]];
      float xg = (float)(tid - PAD) / sigma;
      wexp = expf(-0.5f * xg * xg);
    }
    float s = wexp;
#pragma unroll
    for (int off = 32; off > 0; off >>= 1) s += __shfl_down(s, off);
    float tot = __shfl(s, 0);
    if (tid < 32) gkl[tid] = wexp / tot;
  }
  __syncthreads();

  float acc[32];
#pragma unroll
  for (int yy = 0; yy < 32; yy++) acc[yy] = 0.0f;
#pragma unroll
  for (int kk = 0; kk < KS; kk++) {
    float kv = gkl[kk];
#pragma unroll
    for (int yy = 0; yy < 32; yy++) acc[yy] += kv * xv[yy + kk];
  }
#pragma unroll
  for (int yy = 0; yy < 32; yy++) vsp[yy][tid + 16] = acc[yy];
  __syncthreads();
  {
    int row = tid >> 4, i2 = tid & 15;
#pragma unroll
    for (int r2 = 0; r2 < 2; r2++) {
      int rr = row + 16 * r2;
      vsp[rr][i2] = vsp[rr][32 - i2];
      vsp[rr][272 + i2] = vsp[rr][270 - i2];
    }
  }
  __syncthreads();

  size_t zb = (size_t)bc * (HH * WW);
#pragma unroll
  for (int it = 0; it < 8; ++it) {
    int unit = tid + 256 * it;
    int row = unit >> 6, cg = unit & 63;
    float w[36];
#pragma unroll
    for (int i = 0; i < 9; i++)
      *(float4*)&w[4 * i] = *(const float4*)&vsp[row][4 * (cg + i)];
    float o0 = 0, o1 = 0, o2 = 0, o3 = 0;
#pragma unroll
    for (int kk = 0; kk < KS; kk++) {
      float kv = gkl[kk];
      o0 += kv * w[2 + kk];
      o1 += kv * w[3 + kk];
      o2 += kv * w[4 + kk];
      o3 += kv * w[5 + kk];
    }
    unsigned u0 = pk_bf16(o0, o1);
    unsigned u1 = pk_bf16(o2, o3);
    *(uint2*)&z[zb + (size_t)(y0 + row) * WW + 4 * cg] = make_uint2(u0, u1);
  }
}

// ---------------- fused conv1+ReLU+conv2+MSE via bf16 MFMA ----------------
// grid (16,16,B); block 256 = 4 waves; 16x16 output tile
// conv1: 32x32x16 MFMA; conv2: 16x16x32 loop-rotated; last block reduces.
__global__ __launch_bounds__(256, 5) void convloss_kernel(
    const float* __restrict__ x, float* __restrict__ ws,
    const float* __restrict__ b2g, float* __restrict__ out) {
  __shared__ __align__(16) unsigned short zs4[400 * 4];   // [y*20+x][ci0..2,pad]
  __shared__ __align__(16) unsigned short hs[324 * 40];   // [p18][och(32)+pad8]
  __shared__ float wsum[4];
  __shared__ int amLast;

  const float* tcond = ws + 1024;
  const unsigned short* w1n = (const unsigned short*)(ws + 2048);
  const unsigned short* w2c = (const unsigned short*)(ws + 2816);
  const unsigned short* zg = (const unsigned short*)(ws + 5120);
  float* partial = ws + PARTIAL_OFF;
  int* counter = (int*)(ws + COUNTER_OFF);

  int bx = blockIdx.x, by = blockIdx.y, b = blockIdx.z;
  int tid = threadIdx.x;
  int x0 = bx * 16, y0 = by * 16;
  const unsigned short* zbp = zg + (size_t)b * 3 * HH * WW;

  int lane = tid & 63;
  int q = lane >> 4;        // quad (16x16 shapes)
  int col = lane & 15;      // 16x16 m/n index
  int col32 = lane & 31;    // 32x32 n index (pixel)
  int h = lane >> 5;        // 32x32 half
  int wv = tid >> 6;        // wave id

  // ---- vectorized z staging: 200 threads, 2-px units, b32 loads ----
  if (tid < 200) {
    int zy = tid / 10;
    int zx2 = tid - zy * 10;
    int gy = y0 - 2 + zy;
    int gx0 = x0 - 2 + 2 * zx2;
    bool ok = ((unsigned)gy < (unsigned)HH) && ((unsigned)gx0 < (unsigned)(WW - 1));
    int cy = (gy < 0) ? 0 : ((gy > 255) ? 255 : gy);
    int cx = (gx0 < 0) ? 0 : ((gx0 > 254) ? 254 : gx0);
    int gi = cy * WW + cx;
    unsigned c0 = *(const unsigned*)&zbp[gi];
    unsigned c1 = *(const unsigned*)&zbp[HH * WW + gi];
    unsigned c2 = *(const unsigned*)&zbp[2 * HH * WW + gi];
    unsigned m = ok ? 0xFFFFFFFFu : 0u;
    c0 &= m; c1 &= m; c2 &= m;
    uint4 o;
    o.x = (c0 & 0xFFFFu) | (c1 << 16);        // px0: ci0,ci1
    o.y = c2 & 0xFFFFu;                       // px0: ci2,pad
    o.z = (c0 >> 16) | (c1 & 0xFFFF0000u);    // px1: ci0,ci1
    o.w = c2 >> 16;                           // px1: ci2,pad
    *(uint4*)&zs4[(zy * 20 + 2 * zx2) * 4] = o;
  }

  // conv1 A fragments = weights [m=och][k=slot(h*8+j)]: b128 each
  U4 W0, W1f, W2f;
  W0.u4  = *(const uint4*)(w1n + 0 * 512 + col32 * 16 + h * 8);
  W1f.u4 = *(const uint4*)(w1n + 1 * 512 + col32 * 16 + h * 8);
  W2f.u4 = *(const uint4*)(w1n + 2 * 512 + col32 * 16 + h * 8);

  // conv1 C-init: tcond bias per (reg,h): och = (reg&3) + 8*(reg>>2) + 4h
  f32x16 tc16;
#pragma unroll
  for (int r1 = 0; r1 < 4; r1++) {
    float4 v = *(const float4*)(tcond + b * 32 + 4 * h + 8 * r1);
    tc16[4 * r1 + 0] = v.x;
    tc16[4 * r1 + 1] = v.y;
    tc16[4 * r1 + 2] = v.z;
    tc16[4 * r1 + 3] = v.w;
  }

  int colc = (col < 3) ? col : 0;
  float b2v = b2g[colc];

  __syncthreads();   // B1: z staged

  // per-lane b64 read offsets (ushort units) for the 3 MFMAs' tap pairs
  int oA0 = h ? 8 : 0, oB0 = h ? 80 : 4;
  int oA1 = h ? 160 : 84, oB1 = h ? 164 : 88;
  const int oA2 = 168;

  // ---- P1: conv1 -> h (18x18, 32 och); 32-px groups, 3 MFMAs each ----
#pragma unroll
  for (int i = 0; i < 3; i++) {
    int g = wv + 4 * i;
    if (g < 11) {                 // wave-uniform guard
      int p = g * 32 + col32;
      int pc = (p > 323) ? 323 : p;
      int py = pc / 18, px = pc - py * 18;
      int ub = (py * 20 + px) * 4;
      uint2 l0 = *(const uint2*)&zs4[ub + oA0];
      uint2 l1 = *(const uint2*)&zs4[ub + oB0];
      uint2 l2 = *(const uint2*)&zs4[ub + oA1];
      uint2 l3 = *(const uint2*)&zs4[ub + oB1];
      uint2 l4 = *(const uint2*)&zs4[ub + oA2];
      U4 Bz0, Bz1, Bz2;
      Bz0.u4 = make_uint4(l0.x, l0.y, l1.x, l1.y);
      Bz1.u4 = make_uint4(l2.x, l2.y, l3.x, l3.y);
      Bz2.u4 = make_uint4(l4.x, l4.y, 0u, 0u);
      f32x16 a = __builtin_amdgcn_mfma_f32_32x32x16_bf16(W0.s8, Bz0.s8, tc16, 0, 0, 0);
      a = __builtin_amdgcn_mfma_f32_32x32x16_bf16(W1f.s8, Bz1.s8, a, 0, 0, 0);
      a = __builtin_amdgcn_mfma_f32_32x32x16_bf16(W2f.s8, Bz2.s8, a, 0, 0, 0);
      if (p < 324) {
#pragma unroll
        for (int r1 = 0; r1 < 4; r1++) {
          unsigned u0 = pk_bf16(fmaxf(a[4 * r1 + 0], 0.0f), fmaxf(a[4 * r1 + 1], 0.0f));
          unsigned u1 = pk_bf16(fmaxf(a[4 * r1 + 2], 0.0f), fmaxf(a[4 * r1 + 3], 0.0f));
          *(uint2*)&hs[p * 40 + 4 * h + 8 * r1] = make_uint2(u0, u1);
        }
      }
    }
  }
  __syncthreads();   // B2: h complete

  // prefetch MSE x reads (hidden behind conv2)
  const float* xb = x + (size_t)b * 3 * HH * WW;
  float4 xpre[4];
#pragma unroll
  for (int i = 0; i < 4; i++) {
    int g2 = wv * 4 + i;
    xpre[i] = *(const float4*)&xb[colc * (HH * WW) + (y0 + g2) * WW + x0 + q * 4];
  }

  // hoist all 9 conv2 B-frags: one addr calc, back-to-back loads
  U4 Bt[3][3];
  {
    const unsigned short* wbase = w2c + col * 32 + q * 8;
#pragma unroll
    for (int dy = 0; dy < 3; dy++)
#pragma unroll
      for (int dx = 0; dx < 3; dx++)
        Bt[dy][dx].u4 = *(const uint4*)(wbase + (dy * 3 + dx) * 512);
  }

  // ---- conv2, loop-rotated: 18 A-reads, 36 accumulating MFMAs ----
  const f32x4 bcv = {b2v, b2v, b2v, b2v};
  f32x4 dacc[4];
#pragma unroll
  for (int i = 0; i < 4; i++) dacc[i] = bcv;
  {
    const unsigned short* hbase = &hs[((wv * 4) * 18 + col) * 40 + q * 8];
#pragma unroll
    for (int dx = 0; dx < 3; dx++) {
#pragma unroll
      for (int rr = 0; rr < 6; rr++) {
        U4 A;
        A.u4 = *(const uint4*)&hbase[(rr * 18 + dx) * 40];   // one b128, imm offset
        if (rr < 4)
          dacc[rr] = __builtin_amdgcn_mfma_f32_16x16x32_bf16(A.s8, Bt[0][dx].s8, dacc[rr], 0, 0, 0);
        if (rr >= 1 && rr < 5)
          dacc[rr - 1] = __builtin_amdgcn_mfma_f32_16x16x32_bf16(A.s8, Bt[1][dx].s8, dacc[rr - 1], 0, 0, 0);
        if (rr >= 2)
          dacc[rr - 2] = __builtin_amdgcn_mfma_f32_16x16x32_bf16(A.s8, Bt[2][dx].s8, dacc[rr - 2], 0, 0, 0);
      }
    }
  }

  // ---- MSE partial (oc=col<3, ox=q*4+r, oy=wv*4+i) ----
  float s = 0.0f;
  if (col < 3) {
#pragma unroll
    for (int i = 0; i < 4; i++) {
      float4 xv = xpre[i];
      float d0 = xv.x - dacc[i][0];
      float d1 = xv.y - dacc[i][1];
      float d2 = xv.z - dacc[i][2];
      float d3 = xv.w - dacc[i][3];
      s += d0 * d0 + d1 * d1 + d2 * d2 + d3 * d3;
    }
  }
#pragma unroll
  for (int off = 32; off > 0; off >>= 1) s += __shfl_down(s, off);
  if (lane == 0) wsum[wv] = s;
  __syncthreads();   // B3

  // ---- store partial; last block to finish reduces all 8192 ----
  if (tid == 0) {
    int bid = (b * 16 + by) * 16 + bx;
    partial[bid] = wsum[0] + wsum[1] + wsum[2] + wsum[3];
    __threadfence();                               // device-scope release
    amLast = (atomicAdd(counter, 1) == 8191);
  }
  __syncthreads();   // B4: broadcast amLast
  if (amLast) {
    __threadfence();                               // acquire
    float s2 = 0.0f;
#pragma unroll
    for (int i = 0; i < 8; i++) {
      float4 v = *(const float4*)&partial[(tid + 256 * i) * 4];
      s2 += v.x + v.y + v.z + v.w;
    }
#pragma unroll
    for (int off = 32; off > 0; off >>= 1) s2 += __shfl_down(s2, off);
    if (lane == 0) wsum[wv] = s2;
    __syncthreads();
    if (tid == 0)
      out[0] = (wsum[0] + wsum[1] + wsum[2] + wsum[3]) * (1.0f / 6291456.0f);
  }
}

extern "C" void kernel_launch(void* const* d_in, const int* in_sizes, int n_in,
                              void* d_out, int out_size, void* d_ws, size_t ws_size,
                              hipStream_t stream) {
  const float* x = (const float*)d_in[0];
  const int* t = (const int*)d_in[1];
  const float* W1 = (const float*)d_in[2];
  const float* b1 = (const float*)d_in[3];
  const float* tw = (const float*)d_in[4];
  const float* W2 = (const float*)d_in[5];
  const float* b2 = (const float*)d_in[6];
  const float* sched = (const float*)d_in[7];
  float* out = (float*)d_out;
  float* ws = (float*)d_ws;
  unsigned short* z = (unsigned short*)(ws + 5120);

  blur_kernel<<<BATCH * CH * 8 + 1, 256, 0, stream>>>(x, t, sched, W1, b1, tw, W2, ws, z);
  dim3 grid(16, 16, BATCH);
  convloss_kernel<<<grid, 256, 0, stream>>>(x, ws, b2, out);
}

// Round 15
// 136.670 us; speedup vs baseline: 2.6686x; 2.6686x over previous
//
#include <hip/hip_runtime.h>
#include <hip/hip_bf16.h>

#define BATCH 32
#define CH 3
#define HH 256
#define WW 256
#define KS 29
#define PAD 14
#define NT_F 1000.0f

typedef __attribute__((ext_vector_type(8))) short short8;
typedef __attribute__((ext_vector_type(4))) float f32x4;
typedef __attribute__((ext_vector_type(16))) float f32x16;

union U4 { short8 s8; uint4 u4; };

__device__ inline unsigned short bf16rne(float f) {
  unsigned u = __float_as_uint(f);
  unsigned r = (u + 0x7FFFu + ((u >> 16) & 1u)) >> 16;
  return (unsigned short)r;
}
__device__ inline unsigned pk_bf16(float a, float b) {
  union { __hip_bfloat162 h2; unsigned u; } cv;
  cv.h2 = __float22bfloat162_rn(make_float2(a, b));
  return cv.u;
}

// ws float layout:
//   (unused)  [1024]          @ 0
//   tcond [32][32]            @ 1024
//   w1n   ushort[3][32][16]   @ 2048  ([mf][och][slot]; slot s: tap=mf*4+(s>>2), ci=s&3)
//   w2c   ushort[9][16][32]   @ 2816  ([tap][oc(16)][och] plain order)
//   z     ushort[32][3][256][256] @ 5120  (bf16 blurred)
//   partial float[8192]       @ 3151872
//
// conv1 (32x32x16 MFMA): A=weights[m=och][k=slot], B=z[k=slot][n=pixel],
//   D[n=pixel=lane&31][m=och=(reg&3)+8*(reg>>2)+4*(lane>>5)]
// conv2 (16x16x32 MFMA): hs & w2c in plain och order.
//
// NOTE (r14 lesson): do NOT fold the final reduce into convloss via
// __threadfence + atomic counter — device-scope fence = per-block L2
// writeback across 8 non-coherent XCDs, 6x regression. Stream-ordered
// separate kernel gets the ordering for free.

#define PARTIAL_OFF 3151872

// ---------------- blur (+ embedded weight-prep in block 768) ----------------
__global__ __launch_bounds__(256, 3) void blur_kernel(
    const float* __restrict__ x, const int* __restrict__ t,
    const float* __restrict__ sched, const float* __restrict__ W1,
    const float* __restrict__ b1, const float* __restrict__ tw,
    const float* __restrict__ W2, float* __restrict__ ws,
    unsigned short* __restrict__ z) {
  int blk = blockIdx.x;
  int tid = threadIdx.x;

  if (blk >= BATCH * CH * 8) {
    // ---- weight-prep block (runs once; convloss launches after this kernel)
    float* tcond = ws + 1024;
    unsigned short* w1n = (unsigned short*)(ws + 2048);
    unsigned short* w2c = (unsigned short*)(ws + 2816);
    for (int i = tid; i < 1536; i += 256) {          // w1n [mf][och][slot]
      int mf = i >> 9, r = i & 511;
      int och = r >> 4, s = r & 15;
      int tp = mf * 4 + (s >> 2), ci = s & 3;
      w1n[i] = (ci < 3 && tp < 9) ? bf16rne(W1[och * 27 + ci * 9 + tp])
                                  : (unsigned short)0;
    }
    for (int i = tid; i < 4608; i += 256) {          // w2c [tap][oc][och] plain
      int tap = i >> 9, r = i & 511;
      int n = r >> 5, och = r & 31;
      int dy = tap / 3, dx = tap - dy * 3;
      w2c[i] = (n < 3) ? bf16rne(W2[((n * 32 + och) * 3 + dy) * 3 + dx])
                       : (unsigned short)0;
    }
    for (int i = tid; i < 1024; i += 256) {          // tcond
      int b = i >> 5, o = i & 31;
      tcond[i] = b1[o] + ((float)t[b] * (1.0f / NT_F)) * tw[o];
    }
    return;
  }

  __shared__ float vsp[32][288];   // padded cols: idx = col + 16
  __shared__ float gkl[32];
  int rg = blk & 7;
  int bc = blk >> 3;
  int b = bc / CH;
  int y0 = rg * 32;
  const float* xp = x + (size_t)bc * (HH * WW);

  // issue the 60 column loads first (independent of gk)
  float xv[60];
#pragma unroll
  for (int i = 0; i < 60; i++) {
    int gy = y0 - PAD + i;
    gy = (gy < 0) ? -gy : gy;
    gy = (gy >= HH) ? (2 * HH - 2 - gy) : gy;
    xv[i] = xp[gy * WW + tid];
  }

  // wave 0 computes this batch's gaussian kernel into LDS
  if (tid < 64) {
    float wexp = 0.0f;
    if (tid < KS) {
      float sigma = sched[t[b]];
      float xg = (float)(tid - PAD) / sigma;
      wexp = expf(-0.5f * xg * xg);
    }
    float s = wexp;
#pragma unroll
    for (int off = 32; off > 0; off >>= 1) s += __shfl_down(s, off);
    float tot = __shfl(s, 0);
    if (tid < 32) gkl[tid] = wexp / tot;
  }
  __syncthreads();

  float acc[32];
#pragma unroll
  for (int yy = 0; yy < 32; yy++) acc[yy] = 0.0f;
#pragma unroll
  for (int kk = 0; kk < KS; kk++) {
    float kv = gkl[kk];
#pragma unroll
    for (int yy = 0; yy < 32; yy++) acc[yy] += kv * xv[yy + kk];
  }
#pragma unroll
  for (int yy = 0; yy < 32; yy++) vsp[yy][tid + 16] = acc[yy];
  __syncthreads();
  {
    int row = tid >> 4, i2 = tid & 15;
#pragma unroll
    for (int r2 = 0; r2 < 2; r2++) {
      int rr = row + 16 * r2;
      vsp[rr][i2] = vsp[rr][32 - i2];
      vsp[rr][272 + i2] = vsp[rr][270 - i2];
    }
  }
  __syncthreads();

  size_t zb = (size_t)bc * (HH * WW);
#pragma unroll
  for (int it = 0; it < 8; ++it) {
    int unit = tid + 256 * it;
    int row = unit >> 6, cg = unit & 63;
    float w[36];
#pragma unroll
    for (int i = 0; i < 9; i++)
      *(float4*)&w[4 * i] = *(const float4*)&vsp[row][4 * (cg + i)];
    float o0 = 0, o1 = 0, o2 = 0, o3 = 0;
#pragma unroll
    for (int kk = 0; kk < KS; kk++) {
      float kv = gkl[kk];
      o0 += kv * w[2 + kk];
      o1 += kv * w[3 + kk];
      o2 += kv * w[4 + kk];
      o3 += kv * w[5 + kk];
    }
    unsigned u0 = pk_bf16(o0, o1);
    unsigned u1 = pk_bf16(o2, o3);
    *(uint2*)&z[zb + (size_t)(y0 + row) * WW + 4 * cg] = make_uint2(u0, u1);
  }
}

// ---------------- fused conv1+ReLU+conv2+MSE via bf16 MFMA ----------------
// grid (16,16,B); block 256 = 4 waves; 16x16 output tile
// conv1: 32x32x16 MFMA, 32-px groups; conv2: 16x16x32, loop-rotated.
__global__ __launch_bounds__(256, 5) void convloss_kernel(
    const float* __restrict__ x, const float* __restrict__ ws,
    const float* __restrict__ b2g, float* __restrict__ partial) {
  __shared__ __align__(16) unsigned short zs4[400 * 4];   // [y*20+x][ci0..2,pad]
  __shared__ __align__(16) unsigned short hs[324 * 40];   // [p18][och(32)+pad8]
  __shared__ float wsum[4];

  const float* tcond = ws + 1024;
  const unsigned short* w1n = (const unsigned short*)(ws + 2048);
  const unsigned short* w2c = (const unsigned short*)(ws + 2816);
  const unsigned short* zg = (const unsigned short*)(ws + 5120);

  int bx = blockIdx.x, by = blockIdx.y, b = blockIdx.z;
  int tid = threadIdx.x;
  int x0 = bx * 16, y0 = by * 16;
  const unsigned short* zbp = zg + (size_t)b * 3 * HH * WW;

  int lane = tid & 63;
  int q = lane >> 4;        // quad (16x16 shapes)
  int col = lane & 15;      // 16x16 m/n index
  int col32 = lane & 31;    // 32x32 n index (pixel)
  int h = lane >> 5;        // 32x32 half
  int wv = tid >> 6;        // wave id

  // ---- vectorized z staging: 200 threads, 2-px units, b32 loads ----
  if (tid < 200) {
    int zy = tid / 10;
    int zx2 = tid - zy * 10;
    int gy = y0 - 2 + zy;
    int gx0 = x0 - 2 + 2 * zx2;
    bool ok = ((unsigned)gy < (unsigned)HH) && ((unsigned)gx0 < (unsigned)(WW - 1));
    int cy = (gy < 0) ? 0 : ((gy > 255) ? 255 : gy);
    int cx = (gx0 < 0) ? 0 : ((gx0 > 254) ? 254 : gx0);
    int gi = cy * WW + cx;
    unsigned c0 = *(const unsigned*)&zbp[gi];
    unsigned c1 = *(const unsigned*)&zbp[HH * WW + gi];
    unsigned c2 = *(const unsigned*)&zbp[2 * HH * WW + gi];
    unsigned m = ok ? 0xFFFFFFFFu : 0u;
    c0 &= m; c1 &= m; c2 &= m;
    uint4 o;
    o.x = (c0 & 0xFFFFu) | (c1 << 16);        // px0: ci0,ci1
    o.y = c2 & 0xFFFFu;                       // px0: ci2,pad
    o.z = (c0 >> 16) | (c1 & 0xFFFF0000u);    // px1: ci0,ci1
    o.w = c2 >> 16;                           // px1: ci2,pad
    *(uint4*)&zs4[(zy * 20 + 2 * zx2) * 4] = o;
  }

  // conv1 A fragments = weights [m=och][k=slot(h*8+j)]: b128 each
  U4 W0, W1f, W2f;
  W0.u4  = *(const uint4*)(w1n + 0 * 512 + col32 * 16 + h * 8);
  W1f.u4 = *(const uint4*)(w1n + 1 * 512 + col32 * 16 + h * 8);
  W2f.u4 = *(const uint4*)(w1n + 2 * 512 + col32 * 16 + h * 8);

  // conv1 C-init: tcond bias per (reg,h): och = (reg&3) + 8*(reg>>2) + 4h
  f32x16 tc16;
#pragma unroll
  for (int r1 = 0; r1 < 4; r1++) {
    float4 v = *(const float4*)(tcond + b * 32 + 4 * h + 8 * r1);
    tc16[4 * r1 + 0] = v.x;
    tc16[4 * r1 + 1] = v.y;
    tc16[4 * r1 + 2] = v.z;
    tc16[4 * r1 + 3] = v.w;
  }

  int colc = (col < 3) ? col : 0;
  float b2v = b2g[colc];

  __syncthreads();   // B1: z staged

  // per-lane b64 read offsets (ushort units) for the 3 MFMAs' tap pairs
  int oA0 = h ? 8 : 0, oB0 = h ? 80 : 4;
  int oA1 = h ? 160 : 84, oB1 = h ? 164 : 88;
  const int oA2 = 168;

  // ---- P1: conv1 -> h (18x18, 32 och); 32-px groups, 3 MFMAs each ----
#pragma unroll
  for (int i = 0; i < 3; i++) {
    int g = wv + 4 * i;
    if (g < 11) {                 // wave-uniform guard
      int p = g * 32 + col32;
      int pc = (p > 323) ? 323 : p;
      int py = pc / 18, px = pc - py * 18;
      int ub = (py * 20 + px) * 4;
      uint2 l0 = *(const uint2*)&zs4[ub + oA0];
      uint2 l1 = *(const uint2*)&zs4[ub + oB0];
      uint2 l2 = *(const uint2*)&zs4[ub + oA1];
      uint2 l3 = *(const uint2*)&zs4[ub + oB1];
      uint2 l4 = *(const uint2*)&zs4[ub + oA2];
      U4 Bz0, Bz1, Bz2;
      Bz0.u4 = make_uint4(l0.x, l0.y, l1.x, l1.y);
      Bz1.u4 = make_uint4(l2.x, l2.y, l3.x, l3.y);
      Bz2.u4 = make_uint4(l4.x, l4.y, 0u, 0u);
      f32x16 a = __builtin_amdgcn_mfma_f32_32x32x16_bf16(W0.s8, Bz0.s8, tc16, 0, 0, 0);
      a = __builtin_amdgcn_mfma_f32_32x32x16_bf16(W1f.s8, Bz1.s8, a, 0, 0, 0);
      a = __builtin_amdgcn_mfma_f32_32x32x16_bf16(W2f.s8, Bz2.s8, a, 0, 0, 0);
      if (p < 324) {
#pragma unroll
        for (int r1 = 0; r1 < 4; r1++) {
          unsigned u0 = pk_bf16(fmaxf(a[4 * r1 + 0], 0.0f), fmaxf(a[4 * r1 + 1], 0.0f));
          unsigned u1 = pk_bf16(fmaxf(a[4 * r1 + 2], 0.0f), fmaxf(a[4 * r1 + 3], 0.0f));
          *(uint2*)&hs[p * 40 + 4 * h + 8 * r1] = make_uint2(u0, u1);
        }
      }
    }
  }
  __syncthreads();   // B2: h complete

  // prefetch MSE x reads (hidden behind conv2)
  const float* xb = x + (size_t)b * 3 * HH * WW;
  float4 xpre[4];
#pragma unroll
  for (int i = 0; i < 4; i++) {
    int g2 = wv * 4 + i;
    xpre[i] = *(const float4*)&xb[colc * (HH * WW) + (y0 + g2) * WW + x0 + q * 4];
  }

  // hoist all 9 conv2 B-frags: one addr calc, back-to-back loads
  U4 Bt[3][3];
  {
    const unsigned short* wbase = w2c + col * 32 + q * 8;
#pragma unroll
    for (int dy = 0; dy < 3; dy++)
#pragma unroll
      for (int dx = 0; dx < 3; dx++)
        Bt[dy][dx].u4 = *(const uint4*)(wbase + (dy * 3 + dx) * 512);
  }

  // ---- conv2, loop-rotated: 18 A-reads, 36 accumulating MFMAs ----
  const f32x4 bcv = {b2v, b2v, b2v, b2v};
  f32x4 dacc[4];
#pragma unroll
  for (int i = 0; i < 4; i++) dacc[i] = bcv;
  {
    const unsigned short* hbase = &hs[((wv * 4) * 18 + col) * 40 + q * 8];
#pragma unroll
    for (int dx = 0; dx < 3; dx++) {
#pragma unroll
      for (int rr = 0; rr < 6; rr++) {
        U4 A;
        A.u4 = *(const uint4*)&hbase[(rr * 18 + dx) * 40];   // one b128, imm offset
        if (rr < 4)
          dacc[rr] = __builtin_amdgcn_mfma_f32_16x16x32_bf16(A.s8, Bt[0][dx].s8, dacc[rr], 0, 0, 0);
        if (rr >= 1 && rr < 5)
          dacc[rr - 1] = __builtin_amdgcn_mfma_f32_16x16x32_bf16(A.s8, Bt[1][dx].s8, dacc[rr - 1], 0, 0, 0);
        if (rr >= 2)
          dacc[rr - 2] = __builtin_amdgcn_mfma_f32_16x16x32_bf16(A.s8, Bt[2][dx].s8, dacc[rr - 2], 0, 0, 0);
      }
    }
  }

  // ---- MSE partial (oc=col<3, ox=q*4+r, oy=wv*4+i) ----
  float s = 0.0f;
  if (col < 3) {
#pragma unroll
    for (int i = 0; i < 4; i++) {
      float4 xv = xpre[i];
      float d0 = xv.x - dacc[i][0];
      float d1 = xv.y - dacc[i][1];
      float d2 = xv.z - dacc[i][2];
      float d3 = xv.w - dacc[i][3];
      s += d0 * d0 + d1 * d1 + d2 * d2 + d3 * d3;
    }
  }
#pragma unroll
  for (int off = 32; off > 0; off >>= 1) s += __shfl_down(s, off);
  if (lane == 0) wsum[wv] = s;
  __syncthreads();   // B3
  if (tid == 0) {
    int bid = (b * 16 + by) * 16 + bx;
    partial[bid] = wsum[0] + wsum[1] + wsum[2] + wsum[3];
  }
}

// ---------------- final reduce: 8192 partials -> out[0] ----------------
__global__ __launch_bounds__(256) void reduce_kernel(const float* __restrict__ partial,
                                                     float* __restrict__ out) {
  __shared__ float wsum[4];
  int tid = threadIdx.x;
  float s = 0.0f;
#pragma unroll
  for (int i = 0; i < 8; i++) {
    float4 v = *(const float4*)&partial[(tid + 256 * i) * 4];
    s += v.x + v.y + v.z + v.w;
  }
#pragma unroll
  for (int off = 32; off > 0; off >>= 1) s += __shfl_down(s, off);
  if ((tid & 63) == 0) wsum[tid >> 6] = s;
  __syncthreads();
  if (tid == 0)
    out[0] = (wsum[0] + wsum[1] + wsum[2] + wsum[3]) * (1.0f / 6291456.0f);
}

extern "C" void kernel_launch(void* const* d_in, const int* in_sizes, int n_in,
                              void* d_out, int out_size, void* d_ws, size_t ws_size,
                              hipStream_t stream) {
  const float* x = (const float*)d_in[0];
  const int* t = (const int*)d_in[1];
  const float* W1 = (const float*)d_in[2];
  const float* b1 = (const float*)d_in[3];
  const float* tw = (const float*)d_in[4];
  const float* W2 = (const float*)d_in[5];
  const float* b2 = (const float*)d_in[6];
  const float* sched = (const float*)d_in[7];
  float* out = (float*)d_out;
  float* ws = (float*)d_ws;
  unsigned short* z = (unsigned short*)(ws + 5120);
  float* partial = ws + PARTIAL_OFF;

  blur_kernel<<<BATCH * CH * 8 + 1, 256, 0, stream>>>(x, t, sched, W1, b1, tw, W2, ws, z);
  dim3 grid(16, 16, BATCH);
  convloss_kernel<<<grid, 256, 0, stream>>>(x, ws, b2, partial);
  reduce_kernel<<<1, 256, 0, stream>>>(partial, out);
}